// Round 1
// baseline (515.604 us; speedup 1.0000x reference)
//
#include <hip/hip_runtime.h>

// Cost volume: out[b, o=dy*9+dx, h, w] = leaky( mean_c c1[b,c,h,w] * warped[b,c,h+dy-4,w+dx-4] )
// B=8 C=192 H=128 W=160, 81 offsets, fp32, zero-padded borders.
//
// Structure: 1 block per (b,h) row pair; 192 threads = 9 dy x 20 w-groups (12 idle lanes).
// Each thread: 9dx x 8w register tile (72 acc). warped rows staged in LDS per
// 4-channel chunk (halo zero-filled, row stride 172 floats for alignment/banks);
// c1 read straight from global (L1-broadcast across the 9 dy threads).
// blockIdx = h*8 + b so blockIdx%8==b -> per-XCD batch locality for halo L2 reuse.

namespace {
constexpr int SR   = 4;
constexpr int MO   = 9;            // 2*SR+1
constexpr int NB   = 8;
constexpr int NC   = 192;
constexpr int NH   = 128;
constexpr int NW   = 160;
constexpr int HW   = NH * NW;
constexpr int CC   = 4;            // channels per LDS chunk
constexpr int NCHUNK = NC / CC;    // 48
constexpr int RS   = 172;          // LDS row stride in floats (168 used + pad)
constexpr int NT   = 192;          // block size
constexpr int WGN  = 20;           // w-groups per row
constexpr int WPT  = 8;            // w pixels per thread
constexpr int SEGS = 42;           // float4 segments per padded row (168/4)
constexpr int SLOTS = CC * MO * SEGS;  // 1512 float4 stage slots per chunk
}

__global__ __launch_bounds__(NT, 3)
void costvol_kernel(const float* __restrict__ c1,
                    const float* __restrict__ warped,
                    const float* __restrict__ alphap,
                    float* __restrict__ out)
{
    __shared__ float lds[CC * MO * RS];   // 24768 B

    const int bi  = blockIdx.x;
    const int b   = bi & (NB - 1);        // %8 -> XCD-aligned batch
    const int h   = bi >> 3;
    const int tid = threadIdx.x;
    const int dy  = tid / WGN;            // 0..8 for active threads
    const int g   = tid - dy * WGN;       // 0..19
    const int w0  = g * WPT;
    const bool active = tid < (MO * WGN); // 180 active of 192

    const size_t baseB = (size_t)b * NC * HW;
    const float* c1p   = c1 + baseB + (size_t)h * NW + w0;
    const float* warpB = warped + baseB;

    float acc[MO][WPT];
#pragma unroll
    for (int i = 0; i < MO; ++i)
#pragma unroll
        for (int j = 0; j < WPT; ++j) acc[i][j] = 0.0f;

    for (int chunk = 0; chunk < NCHUNK; ++chunk) {
        const int c0 = chunk * CC;
        __syncthreads();   // protect previous chunk's LDS reads
        // ---- stage CC channels x 9 rows x 168 padded floats into LDS ----
#pragma unroll
        for (int i = 0; i < 8; ++i) {
            const int idx = tid + i * NT;
            if (idx < SLOTS) {
                const int cc  = idx / (MO * SEGS);
                const int rem = idx - cc * (MO * SEGS);
                const int row = rem / SEGS;
                const int seg = rem - row * SEGS;
                const int hr  = h + row - SR;
                float4 v = make_float4(0.f, 0.f, 0.f, 0.f);
                if ((unsigned)hr < (unsigned)NH && seg >= 1 && seg <= 40) {
                    v = *(const float4*)(warpB + (size_t)(c0 + cc) * HW
                                         + (size_t)hr * NW + (seg - 1) * 4);
                }
                *(float4*)&lds[(cc * MO + row) * RS + seg * 4] = v;
            }
        }
        __syncthreads();
        // ---- compute: per channel, 16-float LDS window slides over 9 dx ----
        if (active) {
#pragma unroll
            for (int cc = 0; cc < CC; ++cc) {
                const float* cp = c1p + (size_t)(c0 + cc) * HW;
                const float4 a0 = *(const float4*)(cp);
                const float4 a1 = *(const float4*)(cp + 4);
                const float cv[WPT] = {a0.x, a0.y, a0.z, a0.w,
                                       a1.x, a1.y, a1.z, a1.w};
                const float* lr = &lds[(cc * MO + dy) * RS + w0];
                float win[16];
#pragma unroll
                for (int t = 0; t < 4; ++t) {
                    const float4 v = *(const float4*)(lr + 4 * t);
                    win[4*t+0] = v.x; win[4*t+1] = v.y;
                    win[4*t+2] = v.z; win[4*t+3] = v.w;
                }
#pragma unroll
                for (int dx = 0; dx < MO; ++dx)
#pragma unroll
                    for (int j = 0; j < WPT; ++j)
                        acc[dx][j] = fmaf(cv[j], win[j + dx], acc[dx][j]);
            }
        }
    }

    // ---- epilogue: mean + leaky relu, two float4 stores per dx ----
    if (active) {
        const float scale = 1.0f / (float)NC;
        const float alpha = alphap[0];
        float* op = out + ((size_t)b * (MO * MO) + (size_t)(dy * MO)) * HW
                        + (size_t)h * NW + w0;
#pragma unroll
        for (int dx = 0; dx < MO; ++dx) {
            float r[WPT];
#pragma unroll
            for (int j = 0; j < WPT; ++j) {
                const float v = acc[dx][j] * scale;
                r[j] = (v >= 0.0f) ? v : alpha * v;
            }
            float4* q = (float4*)(op + (size_t)dx * HW);
            q[0] = make_float4(r[0], r[1], r[2], r[3]);
            q[1] = make_float4(r[4], r[5], r[6], r[7]);
        }
    }
}

extern "C" void kernel_launch(void* const* d_in, const int* in_sizes, int n_in,
                              void* d_out, int out_size, void* d_ws, size_t ws_size,
                              hipStream_t stream) {
    (void)in_sizes; (void)n_in; (void)out_size; (void)d_ws; (void)ws_size;
    const float* c1     = (const float*)d_in[0];
    const float* warped = (const float*)d_in[1];
    const float* alpha  = (const float*)d_in[2];
    float* out          = (float*)d_out;
    costvol_kernel<<<dim3(NB * NH), dim3(NT), 0, stream>>>(c1, warped, alpha, out);
}

// Round 3
// 507.175 us; speedup vs baseline: 1.0166x; 1.0166x over previous
//
#include <hip/hip_runtime.h>

// Cost volume: out[b, dy*9+dx, h, w] = leaky( mean_c c1[b,c,h,w] * warped[b,c,h+dy-4,w+dx-4] )
// B=8 C=192 H=128 W=160, 81 offsets, fp32, zero-padded borders.
//
// R3 = R2 + fix: staging LDS writes gated by tid < STG_T (R2 let threads
// 336..383 race zero-writes into live buffers, incl. loff=BUF clobbering the
// other double-buffer).
//
// Structure: 1 block per (b, h-pair); 384 threads = 2 hh x 9 dy x 20 w-groups
// (360 active). 10 warped rows (2 rows + 8 halo) staged per 4-channel chunk into
// double-buffered LDS. Software pipeline: per chunk, issue next chunk's global
// loads -> compute current chunk (hides latency) -> ds_write next chunk.
// One __syncthreads per chunk. Fixed per-thread staging slots: 336 threads x 5
// float4 == 1680 slots exactly; per-chunk address is a pointer bump.
// blockIdx%8 == b pins each batch to one XCD for halo L2 reuse.

namespace {
constexpr int SR   = 4;
constexpr int MO   = 9;
constexpr int NB   = 8;
constexpr int NC   = 192;
constexpr int NH   = 128;
constexpr int NW   = 160;
constexpr int HW   = NH * NW;
constexpr int CC   = 4;              // channels per chunk
constexpr int NCHUNK = NC / CC;      // 48
constexpr int ROWS = 10;             // staged rows: 2 output rows + 8 halo
constexpr int RS   = 172;            // LDS row stride in floats
constexpr int NT   = 384;            // block size (6 waves)
constexpr int WPT  = 8;              // w pixels per thread
constexpr int SEGS = 42;             // float4 segs per padded row
constexpr int STG_T = 336;           // staging threads
constexpr int STG_P = 5;             // float4 slots per staging thread (336*5 == 4*10*42)
constexpr int BUF  = CC * ROWS * RS; // 6880 floats per buffer
}

__global__ __launch_bounds__(NT, 3)
void costvol_kernel(const float* __restrict__ c1,
                    const float* __restrict__ warped,
                    const float* __restrict__ alphap,
                    float* __restrict__ out)
{
    __shared__ float lds[2 * BUF];   // 55040 B -> 2 blocks/CU

    const int bi  = blockIdx.x;
    const int b   = bi & (NB - 1);   // %8 -> XCD-pinned batch
    const int h0  = (bi >> 3) * 2;
    const int tid = threadIdx.x;

    // compute role: hh (which of the 2 output rows), dy, w-group
    const int hh  = tid / 180;
    const int rem = tid - hh * 180;
    const int dy  = rem / 20;
    const int g   = rem - dy * 20;
    const int w0  = g * WPT;
    const bool active = tid < 360;
    const bool stager = tid < STG_T;

    const size_t baseB = (size_t)b * NC * HW;
    const float* warpB = warped + baseB;
    const float* c1p   = c1 + baseB + (size_t)(h0 + hh) * NW + w0;

    // staging role: fixed slot -> (cc,row,seg) mapping, computed once
    int  goff[STG_P], loff[STG_P];
    bool valid[STG_P];
#pragma unroll
    for (int i = 0; i < STG_P; ++i) {
        const int idx = tid + i * STG_T;
        const int cc  = idx / (ROWS * SEGS);
        const int r2  = idx - cc * (ROWS * SEGS);
        const int row = r2 / SEGS;
        const int seg = r2 - row * SEGS;
        const int hr  = h0 + row - SR;
        valid[i] = stager && ((unsigned)hr < (unsigned)NH)
                   && (seg >= 1) && (seg <= 40);
        goff[i]  = cc * HW + hr * NW + (seg - 1) * 4;  // only used when valid
        loff[i]  = (cc * ROWS + row) * RS + seg * 4;
    }

    float acc[MO][WPT];
#pragma unroll
    for (int i = 0; i < MO; ++i)
#pragma unroll
        for (int j = 0; j < WPT; ++j) acc[i][j] = 0.0f;

    // prologue: stage chunk 0 into buffer 0
    {
        float4 v[STG_P];
#pragma unroll
        for (int i = 0; i < STG_P; ++i) {
            v[i] = make_float4(0.f, 0.f, 0.f, 0.f);
            if (valid[i]) v[i] = *(const float4*)(warpB + goff[i]);
        }
        if (stager) {
#pragma unroll
            for (int i = 0; i < STG_P; ++i)
                *(float4*)&lds[loff[i]] = v[i];
        }
    }

    for (int k = 0; k < NCHUNK; ++k) {
        __syncthreads();             // staging of chunk k complete
        const bool more = (k + 1) < NCHUNK;
        float4 v[STG_P];
        if (more) {                  // issue next chunk's loads NOW...
            const float* wk = warpB + (size_t)(k + 1) * (CC * HW);
#pragma unroll
            for (int i = 0; i < STG_P; ++i) {
                v[i] = make_float4(0.f, 0.f, 0.f, 0.f);
                if (valid[i]) v[i] = *(const float4*)(wk + goff[i]);
            }
        }
        // ...compute chunk k while they fly
        if (active) {
            const float* bufp = &lds[(k & 1) * BUF];
            const float* ck   = c1p + (size_t)k * (CC * HW);
#pragma unroll
            for (int cc = 0; cc < CC; ++cc) {
                const float4 a0 = *(const float4*)(ck + (size_t)cc * HW);
                const float4 a1 = *(const float4*)(ck + (size_t)cc * HW + 4);
                const float cv[WPT] = {a0.x, a0.y, a0.z, a0.w,
                                       a1.x, a1.y, a1.z, a1.w};
                const float* lr = bufp + (cc * ROWS + dy + hh) * RS + w0;
                float win[16];
#pragma unroll
                for (int t = 0; t < 4; ++t) {
                    const float4 u = *(const float4*)(lr + 4 * t);
                    win[4*t+0] = u.x; win[4*t+1] = u.y;
                    win[4*t+2] = u.z; win[4*t+3] = u.w;
                }
#pragma unroll
                for (int dx = 0; dx < MO; ++dx)
#pragma unroll
                    for (int j = 0; j < WPT; ++j)
                        acc[dx][j] = fmaf(cv[j], win[j + dx], acc[dx][j]);
            }
        }
        if (more && stager) {        // vmcnt wait lands here, after compute
            float* dst = &lds[((k + 1) & 1) * BUF];
#pragma unroll
            for (int i = 0; i < STG_P; ++i)
                *(float4*)&dst[loff[i]] = v[i];
        }
    }

    // epilogue: mean + leaky relu
    if (active) {
        const float scale = 1.0f / (float)NC;
        const float alpha = alphap[0];
        float* op = out + ((size_t)b * (MO * MO) + (size_t)(dy * MO)) * HW
                        + (size_t)(h0 + hh) * NW + w0;
#pragma unroll
        for (int dx = 0; dx < MO; ++dx) {
            float r[WPT];
#pragma unroll
            for (int j = 0; j < WPT; ++j) {
                const float vv = acc[dx][j] * scale;
                r[j] = (vv >= 0.0f) ? vv : alpha * vv;
            }
            float4* q = (float4*)(op + (size_t)dx * HW);
            q[0] = make_float4(r[0], r[1], r[2], r[3]);
            q[1] = make_float4(r[4], r[5], r[6], r[7]);
        }
    }
}

extern "C" void kernel_launch(void* const* d_in, const int* in_sizes, int n_in,
                              void* d_out, int out_size, void* d_ws, size_t ws_size,
                              hipStream_t stream) {
    (void)in_sizes; (void)n_in; (void)out_size; (void)d_ws; (void)ws_size;
    const float* c1     = (const float*)d_in[0];
    const float* warped = (const float*)d_in[1];
    const float* alpha  = (const float*)d_in[2];
    float* out          = (float*)d_out;
    costvol_kernel<<<dim3(NB * NH / 2), dim3(NT), 0, stream>>>(c1, warped, alpha, out);
}